// Round 1
// baseline (554.726 us; speedup 1.0000x reference)
//
#include <hip/hip_runtime.h>
#include <hip/hip_bf16.h>
#include <cstddef>

// ---------------- problem dims (hard-coded from reference) ----------------
constexpr int cB=4, cN=2000, cT=50, cF=10, cD=64, cR=8, cK=16, cE=32;
constexpr int NODES = cB*cN;     // 8000
constexpr int N1    = cN+1;      // 2001 (padded table incl. zero row m=0)
constexpr int ROWS2 = cB*N1;     // 8004
constexpr int PCHUNKS = (ROWS2 + 63)/64;  // 126

#define DEV static __device__ __forceinline__

DEV float leaky(float x){ return x >= 0.0f ? x : 0.2f*x; }
DEV float rl(float v, int l){ return __int_as_float(__builtin_amdgcn_readlane(__float_as_int(v), l)); }
DEV float wsumall(float v){           // butterfly all-reduce over 64 lanes
  v += __shfl_xor(v,32,64); v += __shfl_xor(v,16,64); v += __shfl_xor(v,8,64);
  v += __shfl_xor(v,4,64);  v += __shfl_xor(v,2,64);  v += __shfl_xor(v,1,64);
  return v;
}
DEV float sigm(float x){ return 1.0f/(1.0f + __expf(-x)); }   // overflow-safe
DEV float tanh_s(float x){                                    // overflow-safe tanh
  float e2 = __expf(2.0f*fabsf(x));
  float t  = 1.0f - 2.0f/(e2 + 1.0f);
  return x >= 0.0f ? t : -t;
}

// ============================ K1: GRU ====================================
// One wave per 4 nodes, lane t owns gate columns {t, 64+t, 128+t}.
// U in LDS, d-interleaved so lane t reads a float4 of U[4d..4d+3][g*64+t].
// h kept in registers; broadcast across lanes via v_readlane (literal idx).
// X rows accessed through a readfirstlane-uniform base -> scalar loads.
__global__ __launch_bounds__(256) void k_gru(const float* __restrict__ X,
    const float* __restrict__ gW, const float* __restrict__ gU,
    const float* __restrict__ gb, float* __restrict__ node)
{
  __shared__ __align__(16) float sU[16][64][12]; // [dq][t][g*4+i] = U[dq*4+i][g*64+t]
  __shared__ float sW[cF][192];
  __shared__ float sb0[192], sb1[192];
  const int tid = threadIdx.x;
  for (int i = tid; i < cD*192; i += 256) {
    int d = i / 192, j = i % 192;
    sU[d>>2][j&63][(j>>6)*4 + (d&3)] = gU[i];
  }
  for (int i = tid; i < cF*192; i += 256) sW[i/192][i%192] = gW[i];
  if (tid < 192) { sb0[tid] = gb[tid]; sb1[tid] = gb[192+tid]; }
  __syncthreads();

  const int lane = tid & 63;
  const int t = lane;
  const int nb = __builtin_amdgcn_readfirstlane((int)blockIdx.x*16 + (tid>>6)*4);
  const float* X0 = X + (size_t)nb * (cT*cF);

  const float bz = sb0[t] + sb1[t];
  const float br = sb0[64+t] + sb1[64+t];
  const float bh0 = sb0[128+t];
  const float bh1 = sb1[128+t];

  float h[4] = {0.f,0.f,0.f,0.f};

  for (int step = 0; step < cT; ++step) {
    float az[4], ar[4], xh[4], rh[4];
    #pragma unroll
    for (int m=0;m<4;++m){ az[m]=bz; ar[m]=br; xh[m]=bh0; rh[m]=bh1; }

    // xp = x @ W (+ biases already in accumulators)
    const float* xp = X0 + step*cF;
    #pragma unroll
    for (int f=0; f<cF; ++f) {
      float wz = sW[f][t], wr = sW[f][64+t], wh = sW[f][128+t];
      #pragma unroll
      for (int m=0;m<4;++m){
        float xv = xp[m*(cT*cF) + f];   // wave-uniform -> scalar load
        az[m] += xv*wz; ar[m] += xv*wr; xh[m] += xv*wh;
      }
    }
    // rec = h @ U
    #pragma unroll
    for (int dq=0; dq<16; ++dq) {
      const float4 uz = *(const float4*)&sU[dq][t][0];
      const float4 ur = *(const float4*)&sU[dq][t][4];
      const float4 uh = *(const float4*)&sU[dq][t][8];
      #pragma unroll
      for (int m=0;m<4;++m){
        float h0 = rl(h[m], 4*dq+0), h1 = rl(h[m], 4*dq+1);
        float h2 = rl(h[m], 4*dq+2), h3 = rl(h[m], 4*dq+3);
        az[m] += h0*uz.x + h1*uz.y + h2*uz.z + h3*uz.w;
        ar[m] += h0*ur.x + h1*ur.y + h2*ur.z + h3*ur.w;
        rh[m] += h0*uh.x + h1*uh.y + h2*uh.z + h3*uh.w;
      }
    }
    // gates
    #pragma unroll
    for (int m=0;m<4;++m){
      float z  = sigm(az[m]);
      float r  = sigm(ar[m]);
      float hh = tanh_s(xh[m] + r*rh[m]);
      h[m] = hh + z*(h[m] - hh);
    }
  }
  #pragma unroll
  for (int m=0;m<4;++m) node[(size_t)(nb+m)*cD + t] = h[m];
}

// ===================== K0: tiny per-relation scalars =====================
__global__ void k_prep(const float* __restrict__ relemb, const float* __restrict__ sattW,
                       const float* __restrict__ sattb, const float* __restrict__ rattW,
                       float* __restrict__ srel, float* __restrict__ rremb)
{
  int r = threadIdx.x;
  if (r < cR){
    float a = 0.f, b2 = 0.f;
    for (int e=0; e<cE; ++e){
      float re = relemb[r*cE + e];
      a  += re * sattW[r*(2*cD+cE) + 2*cD + e];  // w_rel
      b2 += re * rattW[2*cD + e];                 // r_emb
    }
    srel[r]  = a + sattb[r];
    rremb[r] = b2;
  }
}

// =================== K2: projection table + sng table ====================
// act[b,r,m,:] = leaky(padded[b,m]@proj_W[r] + proj_b[r]),  m=0..N (m=0: zero row)
// sng[b,r,m]   = act[b,r,m,:] . w_ngh[r]
// one wave per row, lane = output channel e; proj_W[r] staged in LDS.
__global__ __launch_bounds__(256) void k_proj(const float* __restrict__ node,
    const float* __restrict__ pW, const float* __restrict__ pb,
    const float* __restrict__ sattW, float* __restrict__ act, float* __restrict__ sng)
{
  __shared__ __align__(16) float sP[16][64][4];  // [dq][e][i] = pW[r][dq*4+i][e]
  __shared__ float spb[64], swn[64];
  const int r     = __builtin_amdgcn_readfirstlane((int)blockIdx.x / PCHUNKS);
  const int chunk = __builtin_amdgcn_readfirstlane((int)blockIdx.x % PCHUNKS);
  const int tid = threadIdx.x;
  for (int i=tid; i<cD*cD; i+=256){ int d=i>>6, e=i&63; sP[d>>2][e][d&3] = pW[r*cD*cD + i]; }
  if (tid < 64){ spb[tid] = pb[r*cD + tid]; swn[tid] = sattW[r*(2*cD+cE) + cD + tid]; }
  __syncthreads();

  const int lane = tid & 63, wave = tid >> 6;
  const int e = lane;
  const int qbase = chunk*64 + wave*16;
  for (int j=0; j<16; ++j){
    int q = qbase + j;
    if (q >= ROWS2) break;                 // wave-uniform
    int b = q / N1, m = q % N1;
    float acc = spb[e];
    if (m > 0){
      float v = node[(size_t)(b*cN + m - 1)*cD + lane];
      float p0=0.f,p1=0.f,p2=0.f,p3=0.f;
      #pragma unroll
      for (int dq=0; dq<16; ++dq){
        const float4 w = *(const float4*)&sP[dq][e][0];
        p0 += rl(v,4*dq+0)*w.x;
        p1 += rl(v,4*dq+1)*w.y;
        p2 += rl(v,4*dq+2)*w.z;
        p3 += rl(v,4*dq+3)*w.w;
      }
      acc += (p0+p1)+(p2+p3);
    }
    float o = leaky(acc);
    act[((size_t)(b*cR + r)*N1 + m)*cD + e] = o;
    float s = wsumall(o * swn[e]);
    if (lane == 0) sng[(b*cR + r)*N1 + m] = s;
  }
}

// ================== K3: fused attention + head, 1 wave/(b,n) =============
__global__ __launch_bounds__(256) void k_attn(const float* __restrict__ node,
    const int* __restrict__ nbrs, const float* __restrict__ sattW,
    const float* __restrict__ rattW, const float* __restrict__ rattb,
    const float* __restrict__ predW, const float* __restrict__ predb,
    const float* __restrict__ act, const float* __restrict__ sng,
    const float* __restrict__ srel, const float* __restrict__ rremb,
    float* __restrict__ out)
{
  __shared__ float sSA[cR][cD];        // w_cur rows
  __shared__ float sAtt[4][cR][cK];
  __shared__ int   sOff[4][cR][cK];
  const int tid = threadIdx.x;
  for (int i=tid; i<cR*cD; i+=256) sSA[i>>6][i&63] = sattW[(i>>6)*(2*cD+cE) + (i&63)];
  __syncthreads();

  const int wave = tid >> 6, lane = tid & 63;
  const int gn = (int)blockIdx.x*4 + wave;          // 0..7999
  const int b = __builtin_amdgcn_readfirstlane(gn / cN);
  const int n = __builtin_amdgcn_readfirstlane(gn % cN);

  const float cur = node[(size_t)gn*cD + lane];

  // s_cur[r] via butterfly all-reduce (result in every lane)
  float scr[8];
  #pragma unroll
  for (int r=0; r<8; ++r) scr[r] = wsumall(cur * sSA[r][lane]);

  // scores + per-(r) softmax over k; lane -> (r = half*4 + lane>>4, k = lane&15)
  const int g = lane >> 4, k = lane & 15;
  #pragma unroll
  for (int half=0; half<2; ++half){
    int r = half*4 + g;
    float sc0 = half==0 ? (g==0?scr[0]:g==1?scr[1]:g==2?scr[2]:scr[3])
                        : (g==0?scr[4]:g==1?scr[5]:g==2?scr[6]:scr[7]);
    int idx = nbrs[(((size_t)b*cR + r)*cN + n)*cK + k];
    float sv = sng[(b*cR + r)*N1 + idx];
    float sc = leaky(sc0 + sv + srel[r]);
    if (idx == 0) sc -= 1e9f;
    float mx = sc;
    mx = fmaxf(mx, __shfl_xor(mx,1,64)); mx = fmaxf(mx, __shfl_xor(mx,2,64));
    mx = fmaxf(mx, __shfl_xor(mx,4,64)); mx = fmaxf(mx, __shfl_xor(mx,8,64));
    float ex = __expf(sc - mx);
    float sm = ex;
    sm += __shfl_xor(sm,1,64); sm += __shfl_xor(sm,2,64);
    sm += __shfl_xor(sm,4,64); sm += __shfl_xor(sm,8,64);
    sAtt[wave][r][k] = ex/sm;
    sOff[wave][r][k] = (b*cR + r)*N1 + idx;
  }
  __syncthreads();

  // rel_rep[r][d=lane] = sum_k att * act[row]
  float facc[8];
  #pragma unroll
  for (int r=0; r<8; ++r){
    float a0=0.f, a1=0.f;
    #pragma unroll
    for (int kk=0; kk<cK; kk+=2){
      float w0 = sAtt[wave][r][kk],   w1 = sAtt[wave][r][kk+1];
      int   o0 = sOff[wave][r][kk],   o1 = sOff[wave][r][kk+1];
      a0 += w0 * act[(size_t)o0*cD + lane];
      a1 += w1 * act[(size_t)o1*cD + lane];
    }
    facc[r] = a0 + a1;
  }

  // relation attention
  const float rcur = rattW[lane], rrep = rattW[cD + lane];
  const float rb   = rattb[0];
  const float c0 = wsumall(cur * rcur);
  float rs[8];
  #pragma unroll
  for (int r=0; r<8; ++r) rs[r] = leaky(c0 + wsumall(facc[r]*rrep) + rremb[r] + rb);
  float mx = rs[0];
  #pragma unroll
  for (int r=1; r<8; ++r) mx = fmaxf(mx, rs[r]);
  float es = 0.f; float ratt[8];
  #pragma unroll
  for (int r=0; r<8; ++r){ ratt[r] = __expf(rs[r]-mx); es += ratt[r]; }
  float inv = 1.f/es;
  float agg = 0.f;
  #pragma unroll
  for (int r=0; r<8; ++r) agg += (ratt[r]*inv) * facc[r];
  const float upd = cur + agg;

  // pred head: logits via 3 all-reduces, softmax over L=3
  float l0 = wsumall(upd * predW[lane*3 + 0]);
  float l1 = wsumall(upd * predW[lane*3 + 1]);
  float l2 = wsumall(upd * predW[lane*3 + 2]);
  if (lane == 0){
    l0 += predb[0]; l1 += predb[1]; l2 += predb[2];
    float m2 = fmaxf(l0, fmaxf(l1, l2));
    float e0 = __expf(l0-m2), e1 = __expf(l1-m2), e2 = __expf(l2-m2);
    float is = 1.f/(e0+e1+e2);
    out[(size_t)gn*3+0] = e0*is;
    out[(size_t)gn*3+1] = e1*is;
    out[(size_t)gn*3+2] = e2*is;
  }
}

// ================================ launch =================================
extern "C" void kernel_launch(void* const* d_in, const int* in_sizes, int n_in,
                              void* d_out, int out_size, void* d_ws, size_t ws_size,
                              hipStream_t stream)
{
  const float* X      = (const float*)d_in[0];
  const int*   nbrs   = (const int*)  d_in[1];
  const float* gW     = (const float*)d_in[2];
  const float* gU     = (const float*)d_in[3];
  const float* gb     = (const float*)d_in[4];
  const float* relemb = (const float*)d_in[5];
  const float* pW     = (const float*)d_in[6];
  const float* pb     = (const float*)d_in[7];
  const float* sattW  = (const float*)d_in[8];
  const float* sattb  = (const float*)d_in[9];
  const float* rattW  = (const float*)d_in[10];
  const float* rattb  = (const float*)d_in[11];
  const float* predW  = (const float*)d_in[12];
  const float* predb  = (const float*)d_in[13];
  float* out = (float*)d_out;

  // workspace layout (all fp32), ~18.7 MB total, fully rewritten each call
  float* node  = (float*)d_ws;                       // NODES*cD
  float* act   = node + (size_t)NODES*cD;            // cB*cR*N1*cD
  float* sng   = act  + (size_t)cB*cR*N1*cD;         // cB*cR*N1
  float* srel  = sng  + (size_t)cB*cR*N1;            // cR
  float* rremb = srel + cR;                          // cR

  k_gru <<<NODES/16, 256, 0, stream>>>(X, gW, gU, gb, node);
  k_prep<<<1, 64, 0, stream>>>(relemb, sattW, sattb, rattW, srel, rremb);
  k_proj<<<cR*PCHUNKS, 256, 0, stream>>>(node, pW, pb, sattW, act, sng);
  k_attn<<<NODES/4, 256, 0, stream>>>(node, nbrs, sattW, rattW, rattb,
                                      predW, predb, act, sng, srel, rremb, out);
}

// Round 2
// 165.421 us; speedup vs baseline: 3.3534x; 3.3534x over previous
//
#include <hip/hip_runtime.h>
#include <hip/hip_bf16.h>
#include <cstddef>

// ---------------- problem dims (hard-coded from reference) ----------------
constexpr int cB=4, cN=2000, cT=50, cF=10, cD=64, cR=8, cK=16, cE=32;
constexpr int NODES = cB*cN;     // 8000
constexpr int N1    = cN+1;      // 2001 (padded table incl. zero row m=0)
constexpr int ROWS2 = cB*N1;     // 8004
constexpr int PCHUNKS = (ROWS2 + 63)/64;  // 126

#define DEV static __device__ __forceinline__

typedef __attribute__((ext_vector_type(8))) short bf16x8;   // 8 bf16 = 4 VGPR
typedef __attribute__((ext_vector_type(4))) float f32x4;
typedef __attribute__((ext_vector_type(4))) int   i32x4;

DEV float leaky(float x){ return x >= 0.0f ? x : 0.2f*x; }
DEV float rl(float v, int l){ return __int_as_float(__builtin_amdgcn_readlane(__float_as_int(v), l)); }
DEV float wsumall(float v){           // butterfly all-reduce over 64 lanes
  v += __shfl_xor(v,32,64); v += __shfl_xor(v,16,64); v += __shfl_xor(v,8,64);
  v += __shfl_xor(v,4,64);  v += __shfl_xor(v,2,64);  v += __shfl_xor(v,1,64);
  return v;
}

DEV unsigned fu(float f){ return __float_as_uint(f); }
DEV float hif(float f){ return __uint_as_float(fu(f) & 0xFFFF0000u); }   // truncate to bf16-in-f32
DEV unsigned rne16(float f){                                             // RNE bf16 bits of f
  unsigned u = fu(f);
  return (u + 0x7FFFu + ((u>>16)&1u)) >> 16;
}
DEV bf16x8 pack4(unsigned a, unsigned b, unsigned c2, unsigned d){
  union { i32x4 i; bf16x8 h; } u;
  u.i = (i32x4){(int)a,(int)b,(int)c2,(int)d};
  return u.h;
}
// pair low16(x),low16(y) -> (lo,hi) halves   (low16 holds the hi-bf16 part)
DEV unsigned PLO(unsigned x, unsigned y){ return __builtin_amdgcn_perm(y, x, 0x05040100u); }
// pair high16(x),high16(y)                   (high16 holds the lo-bf16 part)
DEV unsigned PHI(unsigned x, unsigned y){ return __builtin_amdgcn_perm(y, x, 0x07060302u); }

DEV f32x4 MF(bf16x8 a, bf16x8 b, f32x4 c){
  return __builtin_amdgcn_mfma_f32_16x16x32_bf16(a, b, c, 0, 0, 0);
}

// ============================ K1: GRU (MFMA) ==============================
// Block = 128 thr = 2 waves, 16 nodes/block. Wave w owns gate-column slices
// dt in {2w, 2w+1} of each of z/r/h (so z,r,h stay lane-colocated for the
// gate math). Per step, per wave: gates = mfma chain over K-blocks
// [Uhi@h_hi, Uhi@h_lo, Ulo@h_hi, W@x_hi, W@x_lo]; B-frags persistent in
// VGPRs. h crosses steps via a double-buffered, XOR-swizzled LDS tile
// (u32 = hi_bf16 | lo_bf16<<16) that performs the D-layout -> A-layout
// transpose. One __syncthreads per step.
__global__ __launch_bounds__(128, 1) void k_gru(const float* __restrict__ X,
    const float* __restrict__ gW, const float* __restrict__ gU,
    const float* __restrict__ gb, float* __restrict__ node)
{
  __shared__ unsigned sH[2][1024];      // [buf][row*64+col] ^ ((row&7)<<2)

  const int tid  = threadIdx.x;
  const int lane = tid & 63;
  const int w    = tid >> 6;            // wave 0/1
  const int c    = lane & 15;           // MFMA col / A-row(node) index
  const int kg   = lane >> 4;           // k-group
  const int dt0  = 2*w;
  const int nb   = (int)blockIdx.x * 16;

  // ---- persistent B fragments (VGPR) ----
  bf16x8 BUhi[2][6], BUlo[2][6], BW[6];
  #pragma unroll
  for (int s=0;s<2;++s){
    #pragma unroll
    for (int cls=0; cls<3; ++cls){
      #pragma unroll
      for (int i=0;i<2;++i){
        const int n = (cls*4 + dt0 + i)*16 + c;
        unsigned hi[4], lo[4];
        #pragma unroll
        for (int p=0;p<4;++p){
          float u0 = gU[(s*32 + kg*8 + 2*p    )*192 + n];
          float u1 = gU[(s*32 + kg*8 + 2*p + 1)*192 + n];
          hi[p] = (fu(u0)>>16) | (fu(u1) & 0xFFFF0000u);
          lo[p] = rne16(u0 - hif(u0)) | (rne16(u1 - hif(u1)) << 16);
        }
        BUhi[s][cls*2+i] = pack4(hi[0],hi[1],hi[2],hi[3]);
        BUlo[s][cls*2+i] = pack4(lo[0],lo[1],lo[2],lo[3]);
      }
    }
  }
  #pragma unroll
  for (int cls=0; cls<3; ++cls){
    #pragma unroll
    for (int i=0;i<2;++i){
      const int n = (cls*4 + dt0 + i)*16 + c;
      unsigned hi[4];
      #pragma unroll
      for (int p=0;p<4;++p){
        int kx0 = kg*8 + 2*p, kx1 = kx0 + 1;
        float w0 = (kx0 < cF) ? gW[kx0*192 + n] : 0.0f;
        float w1 = (kx1 < cF) ? gW[kx1*192 + n] : 0.0f;
        hi[p] = rne16(w0) | (rne16(w1) << 16);
      }
      BW[cls*2+i] = pack4(hi[0],hi[1],hi[2],hi[3]);
    }
  }

  // ---- biases (per-lane scalars) ----
  float bz[2], br[2], bh0[2], bh1[2];
  #pragma unroll
  for (int i=0;i<2;++i){
    const int col = (dt0+i)*16 + c;
    bz[i]  = gb[col]      + gb[192+col];
    br[i]  = gb[64+col]   + gb[256+col];
    bh0[i] = gb[128+col];
    bh1[i] = gb[320+col];
  }

  // ---- zero h-tile buffer 0 + h registers ----
  for (int i2 = tid; i2 < 1024; i2 += 128) sH[0][i2] = 0u;
  f32x4 ho[2];
  #pragma unroll
  for (int i=0;i<2;++i) ho[i] = (f32x4){0.f,0.f,0.f,0.f};
  __syncthreads();

  // ---- prefetch x for t=0 ----
  float2 xA = {0.f,0.f}, xB = {0.f,0.f}, xC = {0.f,0.f}, xD = {0.f,0.f};
  {
    const float* px = X + ((size_t)(nb + c)*cT + 0)*cF;
    if (kg == 0){ xA = *(const float2*)(px);   xB = *(const float2*)(px+2);
                  xC = *(const float2*)(px+4); xD = *(const float2*)(px+6); }
    else if (kg == 1){ xA = *(const float2*)(px+8); }
  }

  const f32x4 z4 = {0.f,0.f,0.f,0.f};
  const unsigned sw   = (unsigned)((c&7)<<2);
  const unsigned rb0  = (unsigned)(c*64 + kg*8);

  for (int t = 0; t < cT; ++t){
    // ---- build x fragments (x_hi, x_lo) from prefetched regs ----
    float xv[8] = {0.f,0.f,0.f,0.f,0.f,0.f,0.f,0.f};
    if (kg == 0){ xv[0]=xA.x; xv[1]=xA.y; xv[2]=xB.x; xv[3]=xB.y;
                  xv[4]=xC.x; xv[5]=xC.y; xv[6]=xD.x; xv[7]=xD.y; }
    else if (kg == 1){ xv[0]=xA.x; xv[1]=xA.y; }
    unsigned xh_[4], xl_[4];
    #pragma unroll
    for (int p=0;p<4;++p){
      xh_[p] = (fu(xv[2*p])>>16) | (fu(xv[2*p+1]) & 0xFFFF0000u);
      xl_[p] = rne16(xv[2*p] - hif(xv[2*p])) | (rne16(xv[2*p+1] - hif(xv[2*p+1])) << 16);
    }
    bf16x8 xhi = pack4(xh_[0],xh_[1],xh_[2],xh_[3]);
    bf16x8 xlo = pack4(xl_[0],xl_[1],xl_[2],xl_[3]);

    // ---- issue prefetch for t+1 (latency hides under MFMA+gates) ----
    {
      int tn = (t+1 < cT) ? t+1 : cT-1;
      const float* px = X + ((size_t)(nb + c)*cT + tn)*cF;
      if (kg == 0){ xA = *(const float2*)(px);   xB = *(const float2*)(px+2);
                    xC = *(const float2*)(px+4); xD = *(const float2*)(px+6); }
      else if (kg == 1){ xA = *(const float2*)(px+8); }
    }

    // ---- read A fragments of h (hi & lo) from LDS ----
    const unsigned* sr = sH[t & 1];
    i32x4 qa = *(const i32x4*)(sr + ((rb0 +  0) ^ sw));
    i32x4 qb = *(const i32x4*)(sr + ((rb0 +  4) ^ sw));
    i32x4 qc = *(const i32x4*)(sr + ((rb0 + 32) ^ sw));
    i32x4 qd = *(const i32x4*)(sr + ((rb0 + 36) ^ sw));
    bf16x8 hh0 = pack4(PLO(qa[0],qa[1]), PLO(qa[2],qa[3]), PLO(qb[0],qb[1]), PLO(qb[2],qb[3]));
    bf16x8 hl0 = pack4(PHI(qa[0],qa[1]), PHI(qa[2],qa[3]), PHI(qb[0],qb[1]), PHI(qb[2],qb[3]));
    bf16x8 hh1 = pack4(PLO(qc[0],qc[1]), PLO(qc[2],qc[3]), PLO(qd[0],qd[1]), PLO(qd[2],qd[3]));
    bf16x8 hl1 = pack4(PHI(qc[0],qc[1]), PHI(qc[2],qc[3]), PHI(qd[0],qd[1]), PHI(qd[2],qd[3]));

    // ---- MFMA chains ----
    f32x4 aZ[2], aR[2], aHc[2], aXh[2];
    #pragma unroll
    for (int i=0;i<2;++i){
      f32x4 a;
      a = MF(hh0, BUhi[0][0+i], z4); a = MF(hh1, BUhi[1][0+i], a);
      a = MF(hl0, BUhi[0][0+i], a);  a = MF(hl1, BUhi[1][0+i], a);
      a = MF(hh0, BUlo[0][0+i], a);  a = MF(hh1, BUlo[1][0+i], a);
      a = MF(xhi, BW[0+i], a);       a = MF(xlo, BW[0+i], a);
      aZ[i] = a;
      a = MF(hh0, BUhi[0][2+i], z4); a = MF(hh1, BUhi[1][2+i], a);
      a = MF(hl0, BUhi[0][2+i], a);  a = MF(hl1, BUhi[1][2+i], a);
      a = MF(hh0, BUlo[0][2+i], a);  a = MF(hh1, BUlo[1][2+i], a);
      a = MF(xhi, BW[2+i], a);       a = MF(xlo, BW[2+i], a);
      aR[i] = a;
      a = MF(hh0, BUhi[0][4+i], z4); a = MF(hh1, BUhi[1][4+i], a);
      a = MF(hl0, BUhi[0][4+i], a);  a = MF(hl1, BUhi[1][4+i], a);
      a = MF(hh0, BUlo[0][4+i], a);  a = MF(hh1, BUlo[1][4+i], a);
      aHc[i] = a;
      a = MF(xhi, BW[4+i], z4);      a = MF(xlo, BW[4+i], a);
      aXh[i] = a;
    }

    // ---- gates (fp32) + split h -> LDS (other buffer) ----
    unsigned* swr = sH[(t & 1) ^ 1];
    #pragma unroll
    for (int i=0;i<2;++i){
      #pragma unroll
      for (int reg=0; reg<4; ++reg){
        float z  = __builtin_amdgcn_rcpf(1.0f + __expf(-(aZ[i][reg] + bz[i])));
        float r  = __builtin_amdgcn_rcpf(1.0f + __expf(-(aR[i][reg] + br[i])));
        float pre = (aXh[i][reg] + bh0[i]) + r*(aHc[i][reg] + bh1[i]);
        float e2 = __expf(2.0f*fabsf(pre));
        float th = 1.0f - 2.0f*__builtin_amdgcn_rcpf(e2 + 1.0f);
        float hg = copysignf(th, pre);
        float hn = hg + z*(ho[i][reg] - hg);
        ho[i][reg] = hn;
        unsigned val = (fu(hn)>>16) | (rne16(hn - hif(hn)) << 16);
        int row = kg*4 + reg;
        swr[((unsigned)(row*64 + (dt0+i)*16 + c)) ^ ((unsigned)((row&7)<<2))] = val;
      }
    }
    __syncthreads();
  }

  // ---- write out h (fp32) ----
  #pragma unroll
  for (int i=0;i<2;++i){
    #pragma unroll
    for (int reg=0; reg<4; ++reg){
      int row = kg*4 + reg;
      int col = (dt0+i)*16 + c;
      node[(size_t)(nb + row)*cD + col] = ho[i][reg];
    }
  }
}

// ===================== K0: tiny per-relation scalars =====================
__global__ void k_prep(const float* __restrict__ relemb, const float* __restrict__ sattW,
                       const float* __restrict__ sattb, const float* __restrict__ rattW,
                       float* __restrict__ srel, float* __restrict__ rremb)
{
  int r = threadIdx.x;
  if (r < cR){
    float a = 0.f, b2 = 0.f;
    for (int e=0; e<cE; ++e){
      float re = relemb[r*cE + e];
      a  += re * sattW[r*(2*cD+cE) + 2*cD + e];  // w_rel
      b2 += re * rattW[2*cD + e];                 // r_emb
    }
    srel[r]  = a + sattb[r];
    rremb[r] = b2;
  }
}

// =================== K2: projection table + sng table ====================
__global__ __launch_bounds__(256) void k_proj(const float* __restrict__ node,
    const float* __restrict__ pW, const float* __restrict__ pb,
    const float* __restrict__ sattW, float* __restrict__ act, float* __restrict__ sng)
{
  __shared__ __align__(16) float sP[16][64][4];  // [dq][e][i] = pW[r][dq*4+i][e]
  __shared__ float spb[64], swn[64];
  const int r     = __builtin_amdgcn_readfirstlane((int)blockIdx.x / PCHUNKS);
  const int chunk = __builtin_amdgcn_readfirstlane((int)blockIdx.x % PCHUNKS);
  const int tid = threadIdx.x;
  for (int i=tid; i<cD*cD; i+=256){ int d=i>>6, e=i&63; sP[d>>2][e][d&3] = pW[r*cD*cD + i]; }
  if (tid < 64){ spb[tid] = pb[r*cD + tid]; swn[tid] = sattW[r*(2*cD+cE) + cD + tid]; }
  __syncthreads();

  const int lane = tid & 63, wave = tid >> 6;
  const int e = lane;
  const int qbase = chunk*64 + wave*16;
  for (int j=0; j<16; ++j){
    int q = qbase + j;
    if (q >= ROWS2) break;                 // wave-uniform
    int b = q / N1, m = q % N1;
    float acc = spb[e];
    if (m > 0){
      float v = node[(size_t)(b*cN + m - 1)*cD + lane];
      float p0=0.f,p1=0.f,p2=0.f,p3=0.f;
      #pragma unroll
      for (int dq=0; dq<16; ++dq){
        const float4 w2 = *(const float4*)&sP[dq][e][0];
        p0 += rl(v,4*dq+0)*w2.x;
        p1 += rl(v,4*dq+1)*w2.y;
        p2 += rl(v,4*dq+2)*w2.z;
        p3 += rl(v,4*dq+3)*w2.w;
      }
      acc += (p0+p1)+(p2+p3);
    }
    float o = leaky(acc);
    act[((size_t)(b*cR + r)*N1 + m)*cD + e] = o;
    float s = wsumall(o * swn[e]);
    if (lane == 0) sng[(b*cR + r)*N1 + m] = s;
  }
}

// ================== K3: fused attention + head, 1 wave/(b,n) =============
__global__ __launch_bounds__(256) void k_attn(const float* __restrict__ node,
    const int* __restrict__ nbrs, const float* __restrict__ sattW,
    const float* __restrict__ rattW, const float* __restrict__ rattb,
    const float* __restrict__ predW, const float* __restrict__ predb,
    const float* __restrict__ act, const float* __restrict__ sng,
    const float* __restrict__ srel, const float* __restrict__ rremb,
    float* __restrict__ out)
{
  __shared__ float sSA[cR][cD];        // w_cur rows
  __shared__ float sAtt[4][cR][cK];
  __shared__ int   sOff[4][cR][cK];
  const int tid = threadIdx.x;
  for (int i=tid; i<cR*cD; i+=256) sSA[i>>6][i&63] = sattW[(i>>6)*(2*cD+cE) + (i&63)];
  __syncthreads();

  const int wave = tid >> 6, lane = tid & 63;
  const int gn = (int)blockIdx.x*4 + wave;          // 0..7999
  const int b = __builtin_amdgcn_readfirstlane(gn / cN);
  const int n = __builtin_amdgcn_readfirstlane(gn % cN);

  const float cur = node[(size_t)gn*cD + lane];

  float scr[8];
  #pragma unroll
  for (int r=0; r<8; ++r) scr[r] = wsumall(cur * sSA[r][lane]);

  const int g = lane >> 4, k = lane & 15;
  #pragma unroll
  for (int half=0; half<2; ++half){
    int r = half*4 + g;
    float sc0 = half==0 ? (g==0?scr[0]:g==1?scr[1]:g==2?scr[2]:scr[3])
                        : (g==0?scr[4]:g==1?scr[5]:g==2?scr[6]:scr[7]);
    int idx = nbrs[(((size_t)b*cR + r)*cN + n)*cK + k];
    float sv = sng[(b*cR + r)*N1 + idx];
    float sc = leaky(sc0 + sv + srel[r]);
    if (idx == 0) sc -= 1e9f;
    float mx = sc;
    mx = fmaxf(mx, __shfl_xor(mx,1,64)); mx = fmaxf(mx, __shfl_xor(mx,2,64));
    mx = fmaxf(mx, __shfl_xor(mx,4,64)); mx = fmaxf(mx, __shfl_xor(mx,8,64));
    float ex = __expf(sc - mx);
    float sm = ex;
    sm += __shfl_xor(sm,1,64); sm += __shfl_xor(sm,2,64);
    sm += __shfl_xor(sm,4,64); sm += __shfl_xor(sm,8,64);
    sAtt[wave][r][k] = ex/sm;
    sOff[wave][r][k] = (b*cR + r)*N1 + idx;
  }
  __syncthreads();

  float facc[8];
  #pragma unroll
  for (int r=0; r<8; ++r){
    float a0=0.f, a1=0.f;
    #pragma unroll
    for (int kk=0; kk<cK; kk+=2){
      float w0 = sAtt[wave][r][kk],   w1 = sAtt[wave][r][kk+1];
      int   o0 = sOff[wave][r][kk],   o1 = sOff[wave][r][kk+1];
      a0 += w0 * act[(size_t)o0*cD + lane];
      a1 += w1 * act[(size_t)o1*cD + lane];
    }
    facc[r] = a0 + a1;
  }

  const float rcur = rattW[lane], rrep = rattW[cD + lane];
  const float rb   = rattb[0];
  const float c0 = wsumall(cur * rcur);
  float rs[8];
  #pragma unroll
  for (int r=0; r<8; ++r) rs[r] = leaky(c0 + wsumall(facc[r]*rrep) + rremb[r] + rb);
  float mx = rs[0];
  #pragma unroll
  for (int r=1; r<8; ++r) mx = fmaxf(mx, rs[r]);
  float es = 0.f; float ratt[8];
  #pragma unroll
  for (int r=0; r<8; ++r){ ratt[r] = __expf(rs[r]-mx); es += ratt[r]; }
  float inv = 1.f/es;
  float agg = 0.f;
  #pragma unroll
  for (int r=0; r<8; ++r) agg += (ratt[r]*inv) * facc[r];
  const float upd = cur + agg;

  float l0 = wsumall(upd * predW[lane*3 + 0]);
  float l1 = wsumall(upd * predW[lane*3 + 1]);
  float l2 = wsumall(upd * predW[lane*3 + 2]);
  if (lane == 0){
    l0 += predb[0]; l1 += predb[1]; l2 += predb[2];
    float m2 = fmaxf(l0, fmaxf(l1, l2));
    float e0 = __expf(l0-m2), e1 = __expf(l1-m2), e2 = __expf(l2-m2);
    float is = 1.f/(e0+e1+e2);
    out[(size_t)gn*3+0] = e0*is;
    out[(size_t)gn*3+1] = e1*is;
    out[(size_t)gn*3+2] = e2*is;
  }
}

// ================================ launch =================================
extern "C" void kernel_launch(void* const* d_in, const int* in_sizes, int n_in,
                              void* d_out, int out_size, void* d_ws, size_t ws_size,
                              hipStream_t stream)
{
  const float* X      = (const float*)d_in[0];
  const int*   nbrs   = (const int*)  d_in[1];
  const float* gW     = (const float*)d_in[2];
  const float* gU     = (const float*)d_in[3];
  const float* gb     = (const float*)d_in[4];
  const float* relemb = (const float*)d_in[5];
  const float* pW     = (const float*)d_in[6];
  const float* pb     = (const float*)d_in[7];
  const float* sattW  = (const float*)d_in[8];
  const float* sattb  = (const float*)d_in[9];
  const float* rattW  = (const float*)d_in[10];
  const float* rattb  = (const float*)d_in[11];
  const float* predW  = (const float*)d_in[12];
  const float* predb  = (const float*)d_in[13];
  float* out = (float*)d_out;

  float* node  = (float*)d_ws;                       // NODES*cD
  float* act   = node + (size_t)NODES*cD;            // cB*cR*N1*cD
  float* sng   = act  + (size_t)cB*cR*N1*cD;         // cB*cR*N1
  float* srel  = sng  + (size_t)cB*cR*N1;            // cR
  float* rremb = srel + cR;                          // cR

  k_gru <<<NODES/16, 128, 0, stream>>>(X, gW, gU, gb, node);
  k_prep<<<1, 64, 0, stream>>>(relemb, sattW, sattb, rattW, srel, rremb);
  k_proj<<<cR*PCHUNKS, 256, 0, stream>>>(node, pW, pb, sattW, act, sng);
  k_attn<<<NODES/4, 256, 0, stream>>>(node, nbrs, sattW, rattW, rattb,
                                      predW, predb, act, sng, srel, rremb, out);
}

// Round 3
// 114.639 us; speedup vs baseline: 4.8389x; 1.4430x over previous
//
#include <hip/hip_runtime.h>
#include <hip/hip_bf16.h>
#include <cstddef>

// ---------------- problem dims (hard-coded from reference) ----------------
constexpr int cB=4, cN=2000, cT=50, cF=10, cD=64, cR=8, cK=16, cE=32;
constexpr int NODES = cB*cN;     // 8000
constexpr int N1    = cN+1;      // 2001 (padded table incl. zero row m=0)
constexpr int ROWS2 = cB*N1;     // 8004
constexpr int PT    = 8;                      // row-tiles per k_proj block
constexpr int PBLK  = (501 + PT - 1)/PT;      // 63 blocks per r (501 tiles)

#define DEV static __device__ __forceinline__

typedef __attribute__((ext_vector_type(8))) short bf16x8;   // 8 bf16 = 4 VGPR
typedef __attribute__((ext_vector_type(4))) float f32x4;
typedef __attribute__((ext_vector_type(4))) int   i32x4;

DEV float leaky(float x){ return fmaxf(x, 0.2f*x); }
DEV float wsumall(float v){           // butterfly all-reduce over 64 lanes
  v += __shfl_xor(v,32,64); v += __shfl_xor(v,16,64); v += __shfl_xor(v,8,64);
  v += __shfl_xor(v,4,64);  v += __shfl_xor(v,2,64);  v += __shfl_xor(v,1,64);
  return v;
}
DEV unsigned fu(float f){ return __float_as_uint(f); }
DEV float hif(float f){ return __uint_as_float(fu(f) & 0xFFFF0000u); }   // truncate to bf16-in-f32
DEV unsigned rne16(float f){                                             // RNE bf16 bits of f
  unsigned u = fu(f);
  return (u + 0x7FFFu + ((u>>16)&1u)) >> 16;
}
DEV bf16x8 pack4(unsigned a, unsigned b, unsigned c2, unsigned d){
  union { i32x4 i; bf16x8 h; } u;
  u.i = (i32x4){(int)a,(int)b,(int)c2,(int)d};
  return u.h;
}
DEV unsigned PLO(unsigned x, unsigned y){ return __builtin_amdgcn_perm(y, x, 0x05040100u); }
DEV unsigned PHI(unsigned x, unsigned y){ return __builtin_amdgcn_perm(y, x, 0x07060302u); }
DEV f32x4 MF(bf16x8 a, bf16x8 b, f32x4 c){
  return __builtin_amdgcn_mfma_f32_16x16x32_bf16(a, b, c, 0, 0, 0);
}
DEV float bfu(unsigned short u){ return __uint_as_float(((unsigned)u)<<16); }

// ============================ K1: GRU (MFMA) ==============================
// Block = 256 thr = 4 waves over 16 nodes. Wave w owns d-channels
// [16w,16w+16) of each gate (z,r,h~): 3 col-blocks, 21 MFMA/step.
// 500 blocks * 4 waves = 2000 waves -> 2 waves/SIMD for latency hiding.
// Barrier per step is lgkmcnt-only (raw s_barrier): X prefetch (2 steps
// ahead) is never drained by the barrier. h crosses steps via a
// double-buffered XOR-swizzled LDS tile holding (hi|lo<<16) bf16 splits.
__global__ __launch_bounds__(256, 2) void k_gru(const float* __restrict__ X,
    const float* __restrict__ gW, const float* __restrict__ gU,
    const float* __restrict__ gb, float* __restrict__ node)
{
  __shared__ unsigned sH[2][1024];      // [buf][node*64+d] ^ ((node&7)<<2)

  const int tid  = threadIdx.x;
  const int lane = tid & 63;
  const int w    = tid >> 6;            // wave 0..3 -> d-slice
  const int c    = lane & 15;
  const int kg   = lane >> 4;
  const int nb   = (int)blockIdx.x * 16;
  const int col  = 16*w + c;            // d-channel this lane produces

  // ---- persistent B fragments (VGPR): U split hi/lo, W packed (k=2f+s) ----
  bf16x8 BUhi[2][3], BUlo[2][3], BX[3];
  #pragma unroll
  for (int s=0;s<2;++s){
    #pragma unroll
    for (int cls=0; cls<3; ++cls){
      const int n = cls*64 + col;
      unsigned hi[4], lo[4];
      #pragma unroll
      for (int p=0;p<4;++p){
        float u0 = gU[(s*32 + kg*8 + 2*p    )*192 + n];
        float u1 = gU[(s*32 + kg*8 + 2*p + 1)*192 + n];
        hi[p] = (fu(u0)>>16) | (fu(u1) & 0xFFFF0000u);
        lo[p] = rne16(u0 - hif(u0)) | (rne16(u1 - hif(u1)) << 16);
      }
      BUhi[s][cls] = pack4(hi[0],hi[1],hi[2],hi[3]);
      BUlo[s][cls] = pack4(lo[0],lo[1],lo[2],lo[3]);
    }
  }
  #pragma unroll
  for (int cls=0; cls<3; ++cls){
    const int n = cls*64 + col;
    unsigned wd[4];
    #pragma unroll
    for (int p=0;p<4;++p){
      int f = kg*4 + p;
      unsigned v = (f < cF) ? rne16(gW[f*192 + n]) : 0u;
      wd[p] = v | (v << 16);            // k=2f (x_hi) and k=2f+1 (x_lo), same W row
    }
    BX[cls] = pack4(wd[0],wd[1],wd[2],wd[3]);
  }

  // ---- biases -> accumulator init values ----
  const float bz  = gb[col]      + gb[192+col];
  const float br  = gb[64+col]   + gb[256+col];
  const float bh0 = gb[128+col];
  const float bh1 = gb[320+col];

  // ---- zero h-tile buffer 0 + h registers ----
  for (int i2 = tid; i2 < 1024; i2 += 256) sH[0][i2] = 0u;
  f32x4 ho = {0.f,0.f,0.f,0.f};
  __syncthreads();

  // ---- x prefetch, 2 steps ahead; lane kg holds features 4kg..4kg+3 ----
  float xc[4], xn[4];
  const float* Xb = X + (size_t)(nb + c)*cT*cF;
  {
    #pragma unroll
    for (int p=0;p<4;++p){ int f = 4*kg+p; xc[p] = (f < cF) ? Xb[0*cF + f] : 0.f; }
    #pragma unroll
    for (int p=0;p<4;++p){ int f = 4*kg+p; xn[p] = (f < cF) ? Xb[1*cF + f] : 0.f; }
  }

  const unsigned sw  = (unsigned)((c&7)<<2);
  const unsigned rb0 = (unsigned)(c*64 + kg*8);

  for (int t = 0; t < cT; ++t){
    // ---- x A-fragment: word p = hi(xf) | rne-lo(xf)<<16, f = 4kg+p ----
    unsigned xw[4];
    #pragma unroll
    for (int p=0;p<4;++p)
      xw[p] = (fu(xc[p])>>16) | (rne16(xc[p] - hif(xc[p])) << 16);
    bf16x8 xf = pack4(xw[0],xw[1],xw[2],xw[3]);

    // rotate + issue prefetch for t+2 (stays in flight across barrier)
    #pragma unroll
    for (int p=0;p<4;++p) xc[p] = xn[p];
    {
      int tn = (t+2 < cT) ? t+2 : cT-1;
      #pragma unroll
      for (int p=0;p<4;++p){ int f = 4*kg+p; xn[p] = (f < cF) ? Xb[(size_t)tn*cF + f] : 0.f; }
    }

    // ---- read h A-fragments (hi & lo) from LDS ----
    const unsigned* sr = sH[t & 1];
    i32x4 qa = *(const i32x4*)(sr + ((rb0 +  0) ^ sw));
    i32x4 qb = *(const i32x4*)(sr + ((rb0 +  4) ^ sw));
    i32x4 qc = *(const i32x4*)(sr + ((rb0 + 32) ^ sw));
    i32x4 qd = *(const i32x4*)(sr + ((rb0 + 36) ^ sw));
    bf16x8 hh0 = pack4(PLO(qa[0],qa[1]), PLO(qa[2],qa[3]), PLO(qb[0],qb[1]), PLO(qb[2],qb[3]));
    bf16x8 hl0 = pack4(PHI(qa[0],qa[1]), PHI(qa[2],qa[3]), PHI(qb[0],qb[1]), PHI(qb[2],qb[3]));
    bf16x8 hh1 = pack4(PLO(qc[0],qc[1]), PLO(qc[2],qc[3]), PLO(qd[0],qd[1]), PLO(qd[2],qd[3]));
    bf16x8 hl1 = pack4(PHI(qc[0],qc[1]), PHI(qc[2],qc[3]), PHI(qd[0],qd[1]), PHI(qd[2],qd[3]));

    // ---- MFMA: 21 per wave (bias pre-loaded into accumulators) ----
    f32x4 aZ  = {bz,bz,bz,bz};
    f32x4 aR  = {br,br,br,br};
    f32x4 aHc = {bh1,bh1,bh1,bh1};
    f32x4 aXh = {bh0,bh0,bh0,bh0};
    aZ  = MF(xf, BX[0], aZ);
    aR  = MF(xf, BX[1], aR);
    aXh = MF(xf, BX[2], aXh);
    aZ  = MF(hh0, BUhi[0][0], aZ);  aZ  = MF(hh1, BUhi[1][0], aZ);
    aR  = MF(hh0, BUhi[0][1], aR);  aR  = MF(hh1, BUhi[1][1], aR);
    aHc = MF(hh0, BUhi[0][2], aHc); aHc = MF(hh1, BUhi[1][2], aHc);
    aZ  = MF(hl0, BUhi[0][0], aZ);  aZ  = MF(hl1, BUhi[1][0], aZ);
    aR  = MF(hl0, BUhi[0][1], aR);  aR  = MF(hl1, BUhi[1][1], aR);
    aHc = MF(hl0, BUhi[0][2], aHc); aHc = MF(hl1, BUhi[1][2], aHc);
    aZ  = MF(hh0, BUlo[0][0], aZ);  aZ  = MF(hh1, BUlo[1][0], aZ);
    aR  = MF(hh0, BUlo[0][1], aR);  aR  = MF(hh1, BUlo[1][1], aR);
    aHc = MF(hh0, BUlo[0][2], aHc); aHc = MF(hh1, BUlo[1][2], aHc);

    // ---- gates (fp32, branch-free) + split h -> LDS (other buffer) ----
    unsigned* swr = sH[(t & 1) ^ 1];
    #pragma unroll
    for (int reg=0; reg<4; ++reg){
      float z  = __builtin_amdgcn_rcpf(1.0f + __expf(-aZ[reg]));
      float r  = __builtin_amdgcn_rcpf(1.0f + __expf(-aR[reg]));
      float pre = aXh[reg] + r*aHc[reg];
      float th = 1.0f - 2.0f*__builtin_amdgcn_rcpf(__expf(2.0f*pre) + 1.0f);
      float hn = th + z*(ho[reg] - th);
      ho[reg] = hn;
      unsigned val = (fu(hn)>>16) | (rne16(hn - hif(hn)) << 16);
      int nodei = kg*4 + reg;
      swr[((unsigned)(nodei*64 + col)) ^ ((unsigned)((nodei&7)<<2))] = val;
    }
    // lgkmcnt-only barrier: LDS writes visible, X prefetch NOT drained
    asm volatile("s_waitcnt lgkmcnt(0)" ::: "memory");
    __builtin_amdgcn_s_barrier();
  }

  // ---- write out h (fp32) ----
  #pragma unroll
  for (int reg=0; reg<4; ++reg)
    node[(size_t)(nb + kg*4 + reg)*cD + col] = ho[reg];
}

// ===================== K0: tiny per-relation scalars =====================
__global__ void k_prep(const float* __restrict__ relemb, const float* __restrict__ sattW,
                       const float* __restrict__ sattb, const float* __restrict__ rattW,
                       float* __restrict__ srel, float* __restrict__ rremb)
{
  int r = threadIdx.x;
  if (r < cR){
    float a = 0.f, b2 = 0.f;
    for (int e=0; e<cE; ++e){
      float re = relemb[r*cE + e];
      a  += re * sattW[r*(2*cD+cE) + 2*cD + e];  // w_rel
      b2 += re * rattW[2*cD + e];                 // r_emb
    }
    srel[r]  = a + sattb[r];
    rremb[r] = b2;
  }
}

// =================== K2: projection table + sng (MFMA) ====================
// act2[r][q=b*2001+m][e] (bf16) = leaky(padded@pW[r] + pb[r]);
// sng2[r][q] = act . w_ngh[r].  Block: one r, PT row-tiles of 16; wave w
// owns col-block [16w,16w+16); 2 MFMA per tile (K=64, single bf16).
__global__ __launch_bounds__(256) void k_proj(const float* __restrict__ node,
    const float* __restrict__ pW, const float* __restrict__ pb,
    const float* __restrict__ sattW, unsigned short* __restrict__ actb,
    float* __restrict__ sng2)
{
  __shared__ float sngP[4][PT*16];
  const int r  = (int)blockIdx.x / PBLK;
  const int t0 = ((int)blockIdx.x % PBLK) * PT;
  const int tid = threadIdx.x, w = tid>>6, lane = tid&63, c = lane&15, kg = lane>>4;
  const int e = 16*w + c;

  bf16x8 Bw[2];
  #pragma unroll
  for (int s=0;s<2;++s){
    unsigned wd[4];
    #pragma unroll
    for (int p=0;p<4;++p){
      int d = s*32 + kg*8 + 2*p;
      wd[p] = rne16(pW[((size_t)r*cD + d)*cD + e]) |
              (rne16(pW[((size_t)r*cD + d + 1)*cD + e]) << 16);
    }
    Bw[s] = pack4(wd[0],wd[1],wd[2],wd[3]);
  }
  const float bias = pb[r*cD + e];
  const float wn   = sattW[r*(2*cD+cE) + cD + e];

  for (int tt=0; tt<PT; ++tt){
    const int q0 = (t0 + tt)*16;
    const int q  = q0 + c;                       // A-row
    int b = q / N1;
    bool valid = (q < ROWS2) && (q != b*N1);     // q==b*N1 -> m==0 zero row
    int nrow = valid ? (q - b - 1) : 0;          // node row (clamped)
    const float* arow = node + (size_t)nrow*cD;
    bf16x8 Af[2];
    #pragma unroll
    for (int s=0;s<2;++s){
      float v[8];
      #pragma unroll
      for (int j=0;j<8;++j) v[j] = valid ? arow[s*32 + kg*8 + j] : 0.f;
      Af[s] = pack4(rne16(v[0]) | (rne16(v[1])<<16),
                    rne16(v[2]) | (rne16(v[3])<<16),
                    rne16(v[4]) | (rne16(v[5])<<16),
                    rne16(v[6]) | (rne16(v[7])<<16));
    }
    f32x4 acc = {bias,bias,bias,bias};
    acc = MF(Af[0], Bw[0], acc);
    acc = MF(Af[1], Bw[1], acc);
    #pragma unroll
    for (int reg=0; reg<4; ++reg){
      float o = leaky(acc[reg]);
      int qo = q0 + kg*4 + reg;
      if (qo < ROWS2) actb[((size_t)r*ROWS2 + qo)*cD + e] = (unsigned short)rne16(o);
      float s2 = o * wn;
      s2 += __shfl_xor(s2,1,64); s2 += __shfl_xor(s2,2,64);
      s2 += __shfl_xor(s2,4,64); s2 += __shfl_xor(s2,8,64);
      if (c == 0) sngP[w][tt*16 + kg*4 + reg] = s2;
    }
  }
  __syncthreads();
  for (int i = tid; i < PT*16; i += 256){
    int q = t0*16 + i;
    if (q < ROWS2)
      sng2[(size_t)r*ROWS2 + q] = sngP[0][i]+sngP[1][i]+sngP[2][i]+sngP[3][i];
  }
}

// ================== K3: fused attention + head, 1 wave/(b,n) =============
__global__ __launch_bounds__(256) void k_attn(const float* __restrict__ node,
    const int* __restrict__ nbrs, const float* __restrict__ sattW,
    const float* __restrict__ rattW, const float* __restrict__ rattb,
    const float* __restrict__ predW, const float* __restrict__ predb,
    const unsigned short* __restrict__ actb, const float* __restrict__ sng2,
    const float* __restrict__ srel, const float* __restrict__ rremb,
    float* __restrict__ out)
{
  __shared__ float sSA[cR][cD];        // w_cur rows
  __shared__ float sAtt[4][cR][cK];
  __shared__ int   sOff[4][cR][cK];
  const int tid = threadIdx.x;
  for (int i=tid; i<cR*cD; i+=256) sSA[i>>6][i&63] = sattW[(i>>6)*(2*cD+cE) + (i&63)];
  __syncthreads();

  const int wave = tid >> 6, lane = tid & 63;
  const int gn = (int)blockIdx.x*4 + wave;          // 0..7999
  const int b = __builtin_amdgcn_readfirstlane(gn / cN);
  const int n = __builtin_amdgcn_readfirstlane(gn % cN);

  const float cur = node[(size_t)gn*cD + lane];

  float scr[8];
  #pragma unroll
  for (int r=0; r<8; ++r) scr[r] = wsumall(cur * sSA[r][lane]);

  const int g = lane >> 4, k = lane & 15;
  #pragma unroll
  for (int half=0; half<2; ++half){
    int r = half*4 + g;
    float sc0 = half==0 ? (g==0?scr[0]:g==1?scr[1]:g==2?scr[2]:scr[3])
                        : (g==0?scr[4]:g==1?scr[5]:g==2?scr[6]:scr[7]);
    int idx = nbrs[(((size_t)b*cR + r)*cN + n)*cK + k];
    int o = r*ROWS2 + b*N1 + idx;
    float sv = sng2[o];
    float sc = leaky(sc0 + sv + srel[r]);
    if (idx == 0) sc -= 1e9f;
    float mx = sc;
    mx = fmaxf(mx, __shfl_xor(mx,1,64)); mx = fmaxf(mx, __shfl_xor(mx,2,64));
    mx = fmaxf(mx, __shfl_xor(mx,4,64)); mx = fmaxf(mx, __shfl_xor(mx,8,64));
    float ex = __expf(sc - mx);
    float sm = ex;
    sm += __shfl_xor(sm,1,64); sm += __shfl_xor(sm,2,64);
    sm += __shfl_xor(sm,4,64); sm += __shfl_xor(sm,8,64);
    sAtt[wave][r][k] = ex/sm;
    sOff[wave][r][k] = o;
  }
  __syncthreads();

  float facc[8];
  #pragma unroll
  for (int r=0; r<8; ++r){
    float a0=0.f, a1=0.f;
    #pragma unroll
    for (int kk=0; kk<cK; kk+=2){
      float w0 = sAtt[wave][r][kk],   w1 = sAtt[wave][r][kk+1];
      int   o0 = sOff[wave][r][kk],   o1 = sOff[wave][r][kk+1];
      a0 += w0 * bfu(actb[(size_t)o0*cD + lane]);
      a1 += w1 * bfu(actb[(size_t)o1*cD + lane]);
    }
    facc[r] = a0 + a1;
  }

  const float rcur = rattW[lane], rrep = rattW[cD + lane];
  const float rb   = rattb[0];
  const float c0 = wsumall(cur * rcur);
  float rs[8];
  #pragma unroll
  for (int r=0; r<8; ++r) rs[r] = leaky(c0 + wsumall(facc[r]*rrep) + rremb[r] + rb);
  float mx = rs[0];
  #pragma unroll
  for (int r=1; r<8; ++r) mx = fmaxf(mx, rs[r]);
  float es = 0.f; float ratt[8];
  #pragma unroll
  for (int r=0; r<8; ++r){ ratt[r] = __expf(rs[r]-mx); es += ratt[r]; }
  float inv = 1.f/es;
  float agg = 0.f;
  #pragma unroll
  for (int r=0; r<8; ++r) agg += (ratt[r]*inv) * facc[r];
  const float upd = cur + agg;

  float l0 = wsumall(upd * predW[lane*3 + 0]);
  float l1 = wsumall(upd * predW[lane*3 + 1]);
  float l2 = wsumall(upd * predW[lane*3 + 2]);
  if (lane == 0){
    l0 += predb[0]; l1 += predb[1]; l2 += predb[2];
    float m2 = fmaxf(l0, fmaxf(l1, l2));
    float e0 = __expf(l0-m2), e1 = __expf(l1-m2), e2 = __expf(l2-m2);
    float is = 1.f/(e0+e1+e2);
    out[(size_t)gn*3+0] = e0*is;
    out[(size_t)gn*3+1] = e1*is;
    out[(size_t)gn*3+2] = e2*is;
  }
}

// ================================ launch =================================
extern "C" void kernel_launch(void* const* d_in, const int* in_sizes, int n_in,
                              void* d_out, int out_size, void* d_ws, size_t ws_size,
                              hipStream_t stream)
{
  const float* X      = (const float*)d_in[0];
  const int*   nbrs   = (const int*)  d_in[1];
  const float* gW     = (const float*)d_in[2];
  const float* gU     = (const float*)d_in[3];
  const float* gb     = (const float*)d_in[4];
  const float* relemb = (const float*)d_in[5];
  const float* pW     = (const float*)d_in[6];
  const float* pb     = (const float*)d_in[7];
  const float* sattW  = (const float*)d_in[8];
  const float* sattb  = (const float*)d_in[9];
  const float* rattW  = (const float*)d_in[10];
  const float* rattb  = (const float*)d_in[11];
  const float* predW  = (const float*)d_in[12];
  const float* predb  = (const float*)d_in[13];
  float* out = (float*)d_out;

  // workspace: node fp32 | act bf16 (r-major) | sng fp32 | srel | rremb
  float*          node  = (float*)d_ws;                       // NODES*cD
  unsigned short* actb  = (unsigned short*)(node + (size_t)NODES*cD);   // cR*ROWS2*cD bf16
  float*          sng2  = (float*)(actb + (size_t)cR*ROWS2*cD);         // cR*ROWS2
  float*          srel  = sng2 + (size_t)cR*ROWS2;
  float*          rremb = srel + cR;

  k_prep<<<1, 64, 0, stream>>>(relemb, sattW, sattb, rattW, srel, rremb);
  k_gru <<<NODES/16, 256, 0, stream>>>(X, gW, gU, gb, node);
  k_proj<<<cR*PBLK, 256, 0, stream>>>(node, pW, pb, sattW, actb, sng2);
  k_attn<<<NODES/4, 256, 0, stream>>>(node, nbrs, sattW, rattW, rattb,
                                      predW, predb, actb, sng2, srel, rremb, out);
}

// Round 5
// 88.800 us; speedup vs baseline: 6.2469x; 1.2910x over previous
//
#include <hip/hip_runtime.h>
#include <hip/hip_bf16.h>
#include <cstddef>

// ---------------- problem dims (hard-coded from reference) ----------------
constexpr int cB=4, cN=2000, cT=50, cF=10, cD=64, cR=8, cK=16, cE=32;
constexpr int NODES = cB*cN;     // 8000
constexpr int N1    = cN+1;      // 2001 (padded table incl. zero row m=0)
constexpr int ROWS2 = cB*N1;     // 8004

#define DEV static __device__ __forceinline__

typedef __attribute__((ext_vector_type(8))) short bf16x8;   // 8 bf16 = 4 VGPR
typedef __attribute__((ext_vector_type(4))) float f32x4;
typedef __attribute__((ext_vector_type(4))) int   i32x4;

DEV float leaky(float x){ return fmaxf(x, 0.2f*x); }
DEV float wsumall(float v){           // butterfly all-reduce over 64 lanes
  v += __shfl_xor(v,32,64); v += __shfl_xor(v,16,64); v += __shfl_xor(v,8,64);
  v += __shfl_xor(v,4,64);  v += __shfl_xor(v,2,64);  v += __shfl_xor(v,1,64);
  return v;
}
DEV unsigned fu(float f){ return __float_as_uint(f); }
DEV float hif(float f){ return __uint_as_float(fu(f) & 0xFFFF0000u); }   // truncate to bf16-in-f32
DEV unsigned rne16(float f){                                             // RNE bf16 bits of f
  unsigned u = fu(f);
  return (u + 0x7FFFu + ((u>>16)&1u)) >> 16;
}
DEV bf16x8 pack4(unsigned a, unsigned b, unsigned c2, unsigned d){
  union { i32x4 i; bf16x8 h; } u;
  u.i = (i32x4){(int)a,(int)b,(int)c2,(int)d};
  return u.h;
}
DEV unsigned PLO(unsigned x, unsigned y){ return __builtin_amdgcn_perm(y, x, 0x05040100u); }
DEV unsigned PHI(unsigned x, unsigned y){ return __builtin_amdgcn_perm(y, x, 0x07060302u); }
DEV f32x4 MF(bf16x8 a, bf16x8 b, f32x4 c){
  return __builtin_amdgcn_mfma_f32_16x16x32_bf16(a, b, c, 0, 0, 0);
}
DEV float bfu(unsigned short u){ return __uint_as_float(((unsigned)u)<<16); }

// ==================== K1: GRU (MFMA, R3-proven loop) + fused projection ===
// Block = 256 thr = 4 waves over 16 nodes; wave w owns gate d-slice
// [16w,16w+16). 21 MFMA/step/wave; h crosses steps via double-buffered
// XOR-swizzled LDS (hi|lo bf16 splits). lgkmcnt-only barrier per step (X
// prefetch, 2 ahead, never drained). Epilogue: each wave projects the
// block's 16 nodes for r=2w,2w+1 (32 MFMA) -> actb (bf16) + sng2.
__global__ __launch_bounds__(256, 2) void k_gru(const float* __restrict__ X,
    const float* __restrict__ gW, const float* __restrict__ gU,
    const float* __restrict__ gb, const float* __restrict__ pW,
    const float* __restrict__ pb, const float* __restrict__ sattW,
    float* __restrict__ node, unsigned short* __restrict__ actb,
    float* __restrict__ sng2)
{
  __shared__ unsigned sH[2][1024];      // [buf][node*64+d] ^ ((node&7)<<2)

  const int tid  = threadIdx.x;
  const int lane = tid & 63;
  const int w    = tid >> 6;            // wave 0..3 -> d-slice / r-pair
  const int c    = lane & 15;
  const int kg   = lane >> 4;
  const int nb   = (int)blockIdx.x * 16;
  const int col  = 16*w + c;            // d-channel this lane produces
  const int bb   = nb / cN;             // batch (block-uniform, never crosses)

  // ---- persistent B fragments (VGPR): U split hi/lo (RNE), W dup-packed ----
  bf16x8 BUhi[2][3], BUlo[2][3], BX[3];
  #pragma unroll
  for (int s=0;s<2;++s){
    #pragma unroll
    for (int cls=0; cls<3; ++cls){
      const int n = cls*64 + col;
      unsigned hi[4], lo[4];
      #pragma unroll
      for (int p=0;p<4;++p){
        float u0 = gU[(s*32 + kg*8 + 2*p    )*192 + n];
        float u1 = gU[(s*32 + kg*8 + 2*p + 1)*192 + n];
        hi[p] = (fu(u0)>>16) | (fu(u1) & 0xFFFF0000u);
        lo[p] = rne16(u0 - hif(u0)) | (rne16(u1 - hif(u1)) << 16);
      }
      BUhi[s][cls] = pack4(hi[0],hi[1],hi[2],hi[3]);
      BUlo[s][cls] = pack4(lo[0],lo[1],lo[2],lo[3]);
    }
  }
  #pragma unroll
  for (int cls=0; cls<3; ++cls){
    const int n = cls*64 + col;
    unsigned wd[4];
    #pragma unroll
    for (int p=0;p<4;++p){
      int f = kg*4 + p;
      unsigned v = (f < cF) ? rne16(gW[f*192 + n]) : 0u;
      wd[p] = v | (v << 16);            // k=2f (x_hi) and k=2f+1 (x_lo)
    }
    BX[cls] = pack4(wd[0],wd[1],wd[2],wd[3]);
  }

  // ---- biases pre-loaded into accumulator inits ----
  const float bz  = gb[col]      + gb[192+col];
  const float br  = gb[64+col]   + gb[256+col];
  const float bh0 = gb[128+col];
  const float bh1 = gb[320+col];

  // ---- zero h-tile buffer 0 + h registers ----
  for (int i2 = tid; i2 < 1024; i2 += 256) sH[0][i2] = 0u;
  f32x4 ho = {0.f,0.f,0.f,0.f};
  __syncthreads();

  // ---- x prefetch, 2 steps ahead; lane kg holds features 4kg..4kg+3 ----
  float xc[4], xn[4];
  const float* Xb = X + (size_t)(nb + c)*cT*cF;
  {
    #pragma unroll
    for (int p=0;p<4;++p){ int f = 4*kg+p; xc[p] = (f < cF) ? Xb[0*cF + f] : 0.f; }
    #pragma unroll
    for (int p=0;p<4;++p){ int f = 4*kg+p; xn[p] = (f < cF) ? Xb[1*cF + f] : 0.f; }
  }

  const unsigned sw  = (unsigned)((c&7)<<2);
  const unsigned rb0 = (unsigned)(c*64 + kg*8);

  for (int t = 0; t < cT; ++t){
    // ---- x A-fragment: word p = hi(xf) | rne-lo(xf)<<16, f = 4kg+p ----
    unsigned xw[4];
    #pragma unroll
    for (int p=0;p<4;++p)
      xw[p] = (fu(xc[p])>>16) | (rne16(xc[p] - hif(xc[p])) << 16);
    bf16x8 xf = pack4(xw[0],xw[1],xw[2],xw[3]);

    // rotate + issue prefetch for t+2 (stays in flight across barrier)
    #pragma unroll
    for (int p=0;p<4;++p) xc[p] = xn[p];
    {
      int tn = (t+2 < cT) ? t+2 : cT-1;
      #pragma unroll
      for (int p=0;p<4;++p){ int f = 4*kg+p; xn[p] = (f < cF) ? Xb[(size_t)tn*cF + f] : 0.f; }
    }

    // ---- read h A-fragments (hi & lo) from LDS ----
    const unsigned* sr = sH[t & 1];
    i32x4 qa = *(const i32x4*)(sr + ((rb0 +  0) ^ sw));
    i32x4 qb = *(const i32x4*)(sr + ((rb0 +  4) ^ sw));
    i32x4 qc = *(const i32x4*)(sr + ((rb0 + 32) ^ sw));
    i32x4 qd = *(const i32x4*)(sr + ((rb0 + 36) ^ sw));
    bf16x8 hh0 = pack4(PLO(qa[0],qa[1]), PLO(qa[2],qa[3]), PLO(qb[0],qb[1]), PLO(qb[2],qb[3]));
    bf16x8 hl0 = pack4(PHI(qa[0],qa[1]), PHI(qa[2],qa[3]), PHI(qb[0],qb[1]), PHI(qb[2],qb[3]));
    bf16x8 hh1 = pack4(PLO(qc[0],qc[1]), PLO(qc[2],qc[3]), PLO(qd[0],qd[1]), PLO(qd[2],qd[3]));
    bf16x8 hl1 = pack4(PHI(qc[0],qc[1]), PHI(qc[2],qc[3]), PHI(qd[0],qd[1]), PHI(qd[2],qd[3]));

    // ---- MFMA: 21 per wave (bias pre-loaded into accumulators) ----
    f32x4 aZ  = {bz,bz,bz,bz};
    f32x4 aR  = {br,br,br,br};
    f32x4 aHc = {bh1,bh1,bh1,bh1};
    f32x4 aXh = {bh0,bh0,bh0,bh0};
    aZ  = MF(xf, BX[0], aZ);
    aR  = MF(xf, BX[1], aR);
    aXh = MF(xf, BX[2], aXh);
    aZ  = MF(hh0, BUhi[0][0], aZ);  aZ  = MF(hh1, BUhi[1][0], aZ);
    aR  = MF(hh0, BUhi[0][1], aR);  aR  = MF(hh1, BUhi[1][1], aR);
    aHc = MF(hh0, BUhi[0][2], aHc); aHc = MF(hh1, BUhi[1][2], aHc);
    aZ  = MF(hl0, BUhi[0][0], aZ);  aZ  = MF(hl1, BUhi[1][0], aZ);
    aR  = MF(hl0, BUhi[0][1], aR);  aR  = MF(hl1, BUhi[1][1], aR);
    aHc = MF(hl0, BUhi[0][2], aHc); aHc = MF(hl1, BUhi[1][2], aHc);
    aZ  = MF(hh0, BUlo[0][0], aZ);  aZ  = MF(hh1, BUlo[1][0], aZ);
    aR  = MF(hh0, BUlo[0][1], aR);  aR  = MF(hh1, BUlo[1][1], aR);
    aHc = MF(hh0, BUlo[0][2], aHc); aHc = MF(hh1, BUlo[1][2], aHc);

    // ---- gates (fp32, branch-free) + split h -> LDS (other buffer) ----
    unsigned* swr = sH[(t & 1) ^ 1];
    #pragma unroll
    for (int reg=0; reg<4; ++reg){
      float z  = __builtin_amdgcn_rcpf(1.0f + __expf(-aZ[reg]));
      float r  = __builtin_amdgcn_rcpf(1.0f + __expf(-aR[reg]));
      float pre = __builtin_fmaf(r, aHc[reg], aXh[reg]);
      float th = 1.0f - 2.0f*__builtin_amdgcn_rcpf(__expf(2.0f*pre) + 1.0f);
      float hn = __builtin_fmaf(z, ho[reg]-th, th);
      ho[reg] = hn;
      unsigned val = (fu(hn)>>16) | (rne16(hn - hif(hn)) << 16);
      int nodei = kg*4 + reg;
      swr[((unsigned)(nodei*64 + col)) ^ ((unsigned)((nodei&7)<<2))] = val;
    }
    // lgkmcnt-only barrier: LDS writes visible, X prefetch NOT drained
    asm volatile("s_waitcnt lgkmcnt(0)" ::: "memory");
    __builtin_amdgcn_s_barrier();
  }

  // ---- write out h (fp32) for k_attn ----
  #pragma unroll
  for (int reg=0; reg<4; ++reg)
    node[(size_t)(nb + kg*4 + reg)*cD + col] = ho[reg];

  // ================= fused projection epilogue =================
  // final h (hi|lo) is in sH[0] (t=49 wrote buf 0; barrier passed)
  {
    const unsigned* sr = &sH[0][0];
    i32x4 qa = *(const i32x4*)(sr + ((rb0 +  0) ^ sw));
    i32x4 qb = *(const i32x4*)(sr + ((rb0 +  4) ^ sw));
    i32x4 qc = *(const i32x4*)(sr + ((rb0 + 32) ^ sw));
    i32x4 qd = *(const i32x4*)(sr + ((rb0 + 36) ^ sw));
    bf16x8 hh0 = pack4(PLO(qa[0],qa[1]), PLO(qa[2],qa[3]), PLO(qb[0],qb[1]), PLO(qb[2],qb[3]));
    bf16x8 hl0 = pack4(PHI(qa[0],qa[1]), PHI(qa[2],qa[3]), PHI(qb[0],qb[1]), PHI(qb[2],qb[3]));
    bf16x8 hh1 = pack4(PLO(qc[0],qc[1]), PLO(qc[2],qc[3]), PLO(qd[0],qd[1]), PLO(qd[2],qd[3]));
    bf16x8 hl1 = pack4(PHI(qc[0],qc[1]), PHI(qc[2],qc[3]), PHI(qd[0],qd[1]), PHI(qd[2],qd[3]));

    const int qbase = nb + bb + 1;        // padded-table row of node nb
    #pragma unroll
    for (int r2=0; r2<2; ++r2){
      const int r = 2*w + r2;
      const float* Pr = pW + (size_t)r*cD*cD;
      bf16x8 PB[4][2];
      float pbv[4], wnv[4];
      #pragma unroll
      for (int cb=0; cb<4; ++cb){
        const int e = 16*cb + c;
        #pragma unroll
        for (int s=0;s<2;++s){
          unsigned wd[4];
          #pragma unroll
          for (int p=0;p<4;++p){
            int k0 = s*32 + kg*8 + 2*p;
            wd[p] = rne16(Pr[(size_t)k0*cD + e]) | (rne16(Pr[(size_t)(k0+1)*cD + e]) << 16);
          }
          PB[cb][s] = pack4(wd[0],wd[1],wd[2],wd[3]);
        }
        pbv[cb] = pb[r*cD + e];
        wnv[cb] = sattW[r*(2*cD+cE) + cD + e];
      }
      float sp[4] = {0.f,0.f,0.f,0.f};
      #pragma unroll
      for (int cb=0; cb<4; ++cb){
        f32x4 acc = {pbv[cb],pbv[cb],pbv[cb],pbv[cb]};
        acc = MF(hh0, PB[cb][0], acc); acc = MF(hh1, PB[cb][1], acc);
        acc = MF(hl0, PB[cb][0], acc); acc = MF(hl1, PB[cb][1], acc);
        #pragma unroll
        for (int reg=0; reg<4; ++reg){
          float o = leaky(acc[reg]);
          int qrow = qbase + kg*4 + reg;
          actb[((size_t)r*ROWS2 + qrow)*cD + 16*cb + c] = (unsigned short)rne16(o);
          sp[reg] = __builtin_fmaf(o, wnv[cb], sp[reg]);
        }
      }
      #pragma unroll
      for (int reg=0; reg<4; ++reg){
        float s2 = sp[reg];
        s2 += __shfl_xor(s2,1,64); s2 += __shfl_xor(s2,2,64);
        s2 += __shfl_xor(s2,4,64); s2 += __shfl_xor(s2,8,64);
        if (c == 0) sng2[(size_t)r*ROWS2 + qbase + kg*4 + reg] = s2;
      }
    }
  }

  // ---- 4 designated blocks write the m=0 (zero-input) rows ----
  if ((blockIdx.x % (cN/16)) == 0){
    #pragma unroll
    for (int r2=0; r2<2; ++r2){
      const int r = 2*w + r2;
      float v0 = leaky(pb[r*cD + lane]);
      float wv = sattW[r*(2*cD+cE) + cD + lane];
      actb[((size_t)r*ROWS2 + (size_t)bb*N1)*cD + lane] = (unsigned short)rne16(v0);
      float s2 = wsumall(v0 * wv);
      if (lane == 0) sng2[(size_t)r*ROWS2 + (size_t)bb*N1] = s2;
    }
  }
}

// ============ K3: fused attention + head (+ per-r scalars), 1 wave/(b,n) ==
__global__ __launch_bounds__(256) void k_attn(const float* __restrict__ node,
    const int* __restrict__ nbrs, const float* __restrict__ sattW,
    const float* __restrict__ sattb, const float* __restrict__ rattW,
    const float* __restrict__ rattb, const float* __restrict__ predW,
    const float* __restrict__ predb, const float* __restrict__ relemb,
    const unsigned short* __restrict__ actb, const float* __restrict__ sng2,
    float* __restrict__ out)
{
  __shared__ float sSA[cR][cD];        // w_cur rows
  __shared__ float sSrel[cR], sRremb[cR];
  __shared__ float sAtt[4][cR][cK];
  __shared__ int   sOff[4][cR][cK];
  const int tid = threadIdx.x;
  for (int i=tid; i<cR*cD; i+=256) sSA[i>>6][i&63] = sattW[(i>>6)*(2*cD+cE) + (i&63)];
  if (tid < 64){                       // fold old k_prep: srel, rremb
    int r = tid >> 3, j0 = (tid & 7)*4;
    float a = 0.f, b2 = 0.f;
    #pragma unroll
    for (int j=0;j<4;++j){
      float re = relemb[r*cE + j0 + j];
      a  += re * sattW[r*(2*cD+cE) + 2*cD + j0 + j];
      b2 += re * rattW[2*cD + j0 + j];
    }
    a  += __shfl_xor(a,1,64);  a  += __shfl_xor(a,2,64);  a  += __shfl_xor(a,4,64);
    b2 += __shfl_xor(b2,1,64); b2 += __shfl_xor(b2,2,64); b2 += __shfl_xor(b2,4,64);
    if ((tid & 7) == 0){ sSrel[r] = a + sattb[r]; sRremb[r] = b2; }
  }
  __syncthreads();

  const int wave = tid >> 6, lane = tid & 63;
  const int gn = (int)blockIdx.x*4 + wave;          // 0..7999
  const int b = __builtin_amdgcn_readfirstlane(gn / cN);
  const int n = __builtin_amdgcn_readfirstlane(gn % cN);

  const float cur = node[(size_t)gn*cD + lane];

  float scr[8];
  #pragma unroll
  for (int r=0; r<8; ++r) scr[r] = wsumall(cur * sSA[r][lane]);

  const int g = lane >> 4, k = lane & 15;
  #pragma unroll
  for (int half=0; half<2; ++half){
    int r = half*4 + g;
    float sc0 = half==0 ? (g==0?scr[0]:g==1?scr[1]:g==2?scr[2]:scr[3])
                        : (g==0?scr[4]:g==1?scr[5]:g==2?scr[6]:scr[7]);
    int idx = nbrs[(((size_t)b*cR + r)*cN + n)*cK + k];
    int o = r*ROWS2 + b*N1 + idx;
    float sv = sng2[o];
    float sc = leaky(sc0 + sv + sSrel[r]);
    if (idx == 0) sc -= 1e9f;
    float mx = sc;
    mx = fmaxf(mx, __shfl_xor(mx,1,64)); mx = fmaxf(mx, __shfl_xor(mx,2,64));
    mx = fmaxf(mx, __shfl_xor(mx,4,64)); mx = fmaxf(mx, __shfl_xor(mx,8,64));
    float ex = __expf(sc - mx);
    float sm = ex;
    sm += __shfl_xor(sm,1,64); sm += __shfl_xor(sm,2,64);
    sm += __shfl_xor(sm,4,64); sm += __shfl_xor(sm,8,64);
    sAtt[wave][r][k] = ex/sm;
    sOff[wave][r][k] = o;
  }
  __syncthreads();

  float facc[8];
  #pragma unroll
  for (int r=0; r<8; ++r){
    float a0=0.f, a1=0.f;
    #pragma unroll
    for (int kk=0; kk<cK; kk+=2){
      float w0 = sAtt[wave][r][kk],   w1 = sAtt[wave][r][kk+1];
      int   o0 = sOff[wave][r][kk],   o1 = sOff[wave][r][kk+1];
      a0 += w0 * bfu(actb[(size_t)o0*cD + lane]);
      a1 += w1 * bfu(actb[(size_t)o1*cD + lane]);
    }
    facc[r] = a0 + a1;
  }

  const float rcur = rattW[lane], rrep = rattW[cD + lane];
  const float rb   = rattb[0];
  const float c0 = wsumall(cur * rcur);
  float rs[8];
  #pragma unroll
  for (int r=0; r<8; ++r) rs[r] = leaky(c0 + wsumall(facc[r]*rrep) + sRremb[r] + rb);
  float mx = rs[0];
  #pragma unroll
  for (int r=1; r<8; ++r) mx = fmaxf(mx, rs[r]);
  float es = 0.f; float ratt[8];
  #pragma unroll
  for (int r=0; r<8; ++r){ ratt[r] = __expf(rs[r]-mx); es += ratt[r]; }
  float inv = 1.f/es;
  float agg = 0.f;
  #pragma unroll
  for (int r=0; r<8; ++r) agg += (ratt[r]*inv) * facc[r];
  const float upd = cur + agg;

  float l0 = wsumall(upd * predW[lane*3 + 0]);
  float l1 = wsumall(upd * predW[lane*3 + 1]);
  float l2 = wsumall(upd * predW[lane*3 + 2]);
  if (lane == 0){
    l0 += predb[0]; l1 += predb[1]; l2 += predb[2];
    float m2 = fmaxf(l0, fmaxf(l1, l2));
    float e0 = __expf(l0-m2), e1 = __expf(l1-m2), e2 = __expf(l2-m2);
    float is = 1.f/(e0+e1+e2);
    out[(size_t)gn*3+0] = e0*is;
    out[(size_t)gn*3+1] = e1*is;
    out[(size_t)gn*3+2] = e2*is;
  }
}

// ================================ launch =================================
extern "C" void kernel_launch(void* const* d_in, const int* in_sizes, int n_in,
                              void* d_out, int out_size, void* d_ws, size_t ws_size,
                              hipStream_t stream)
{
  const float* X      = (const float*)d_in[0];
  const int*   nbrs   = (const int*)  d_in[1];
  const float* gW     = (const float*)d_in[2];
  const float* gU     = (const float*)d_in[3];
  const float* gb     = (const float*)d_in[4];
  const float* relemb = (const float*)d_in[5];
  const float* pW     = (const float*)d_in[6];
  const float* pb     = (const float*)d_in[7];
  const float* sattW  = (const float*)d_in[8];
  const float* sattb  = (const float*)d_in[9];
  const float* rattW  = (const float*)d_in[10];
  const float* rattb  = (const float*)d_in[11];
  const float* predW  = (const float*)d_in[12];
  const float* predb  = (const float*)d_in[13];
  float* out = (float*)d_out;

  // workspace: node fp32 | act bf16 (r-major) | sng fp32
  float*          node  = (float*)d_ws;                                 // NODES*cD
  unsigned short* actb  = (unsigned short*)(node + (size_t)NODES*cD);   // cR*ROWS2*cD bf16
  float*          sng2  = (float*)(actb + (size_t)cR*ROWS2*cD);         // cR*ROWS2

  k_gru <<<NODES/16, 256, 0, stream>>>(X, gW, gU, gb, pW, pb, sattW,
                                       node, actb, sng2);
  k_attn<<<NODES/4, 256, 0, stream>>>(node, nbrs, sattW, sattb, rattW, rattb,
                                      predW, predb, relemb, actb, sng2, out);
}